// Round 1
// baseline (1570.280 us; speedup 1.0000x reference)
//
#include <hip/hip_runtime.h>
#include <hip/hip_fp16.h>

typedef _Float16 f16;
typedef _Float16 f16x8 __attribute__((ext_vector_type(8)));
typedef _Float16 f16x4 __attribute__((ext_vector_type(4)));
typedef float f32x4 __attribute__((ext_vector_type(4)));

#define NH 12
#define NWIN 4096
// tokens per window = 64, head dim = 32, DIM = 384, qkv N = 1152

__device__ __forceinline__ void gload16(const void* g, void* l) {
  __builtin_amdgcn_global_load_lds(
      (const __attribute__((address_space(1))) void*)g,
      (__attribute__((address_space(3))) void*)l, 16, 0, 0);
}

// ---------------- prep kernels ----------------

__global__ __launch_bounds__(256) void k_cvt_x(const float* __restrict__ in,
                                               f16* __restrict__ out, long n4) {
  long i = (long)blockIdx.x * 256 + threadIdx.x;
  long stride = (long)gridDim.x * 256;
  for (; i < n4; i += stride) {
    float4 v = ((const float4*)in)[i];
    f16x4 o = {(f16)v.x, (f16)v.y, (f16)v.z, (f16)v.w};
    ((f16x4*)out)[i] = o;
  }
}

// out[n*K + k] = in[k*N + n]  (cast to f16)
__global__ __launch_bounds__(256) void k_transpose(const float* __restrict__ in,
                                                   f16* __restrict__ out, int K, int N) {
  long i = (long)blockIdx.x * 256 + threadIdx.x;
  if (i >= (long)K * N) return;
  int n = (int)(i / K);
  int k = (int)(i - (long)n * K);
  out[i] = (f16)in[(long)k * N + n];
}

// continuous position bias: bias[h][p] = 16*sigmoid( MLP(table[rel_pos_index[p]]) . w2[:,h] )
__global__ __launch_bounds__(64) void k_cpb(const float* __restrict__ table,
                                            const int* __restrict__ ridx,
                                            const float* __restrict__ w1,
                                            const float* __restrict__ b1,
                                            const float* __restrict__ w2,
                                            float* __restrict__ biasout) {
  int p = blockIdx.x * 64 + threadIdx.x;  // 0..4095
  int idx = ridx[p];
  float t0 = table[idx * 2], t1 = table[idx * 2 + 1];
  float acc[NH] = {};
  for (int u = 0; u < 512; u++) {
    float hv = fmaxf(t0 * w1[u] + t1 * w1[512 + u] + b1[u], 0.f);
#pragma unroll
    for (int h = 0; h < NH; h++) acc[h] += hv * w2[u * NH + h];
  }
  for (int h = 0; h < NH; h++) biasout[h * 4096 + p] = 16.f / (1.f + __expf(-acc[h]));
}

// ---------------- GEMM: C[M x N] = A[M x K] * Bt[N x K]^T + bias ----------------
// MODE 0: qkv gemm (N=1152), f16 out to [3][b*12+h][64][32] via LDS repack +
//         coalesced f16x8 stores (384 = 3*128 -> 'which' is constant per block;
//         tile = 8 contiguous 4KB chunks: 2 windows x 4 heads x [64][32])
// MODE 1: proj gemm (N=384), fp32 out row-major [M][384]
template <int MODE, int NXB>
__global__ __launch_bounds__(256) void k_gemm(const f16* __restrict__ A,
                                              const f16* __restrict__ Bt,
                                              const float* __restrict__ bias,
                                              void* __restrict__ out, int K) {
  // MODE 0 reuses the staging LDS for the epilogue repack: [8][64][40] f16.
  // pad 32->40 keeps every row 16B-aligned (80B stride) and makes the
  // acc->LDS write pattern a free 2-way bank alias instead of 4-way.
  __shared__ f16 smem[(MODE == 0) ? (8 * 64 * 40) : (2 * 128 * 32)];
  f16* As = smem;
  f16* Bs = smem + 128 * 32;
  const int lin = blockIdx.x;
  // XCD swizzle: all NXB column-blocks of one row-block share lin%8 -> same XCD L2
  const int idx = lin % (NXB * 8);
  const int xn = idx >> 3;
  const int ym = (lin / (NXB * 8)) * 8 + (idx & 7);
  const int tid = threadIdx.x;
  const int lane = tid & 63, wid = tid >> 6;
  const int wm = wid & 1, wn = wid >> 1;

  f32x4 acc[4][4] = {};
  const long arow = (long)ym * 128;
  const long brow = (long)xn * 128;

  for (int kk = 0; kk < K; kk += 32) {
    __syncthreads();
#pragma unroll
    for (int j = 0; j < 2; j++) {
      int r = wid * 32 + j * 16 + (lane >> 2);
      int co = kk + (lane & 3) * 8;
      gload16(A + (arow + r) * K + co, As + (wid * 32 + j * 16) * 32);
      gload16(Bt + (brow + r) * K + co, Bs + (wid * 32 + j * 16) * 32);
    }
    __syncthreads();
    f16x8 am[4], bn[4];
#pragma unroll
    for (int t = 0; t < 4; t++) {
      am[t] = *(const f16x8*)&As[(wm * 64 + t * 16 + (lane & 15)) * 32 + (lane >> 4) * 8];
      bn[t] = *(const f16x8*)&Bs[(wn * 64 + t * 16 + (lane & 15)) * 32 + (lane >> 4) * 8];
    }
#pragma unroll
    for (int mt = 0; mt < 4; mt++)
#pragma unroll
      for (int nt = 0; nt < 4; nt++)
        acc[mt][nt] = __builtin_amdgcn_mfma_f32_16x16x32_f16(am[mt], bn[nt], acc[mt][nt], 0, 0, 0);
  }

  const int quad = lane >> 4, col0 = lane & 15;
  if constexpr (MODE == 0) {
    // ---- epilogue: acc -> LDS (output-chunk layout) -> coalesced stores ----
    __syncthreads();  // all waves done reading As/Bs before overwrite
#pragma unroll
    for (int nt = 0; nt < 4; nt++) {
      const int hsel = wn * 2 + (nt >> 1);          // head slot 0..3 in block
      const int d = (nt & 1) * 16 + col0;           // dim 0..31
      const float bc = bias[xn * 128 + wn * 64 + nt * 16 + col0];
      f16* cbase = smem + ((wm * 4 + hsel) * 64) * 40 + d;
#pragma unroll
      for (int mt = 0; mt < 4; mt++)
#pragma unroll
        for (int reg = 0; reg < 4; reg++) {
          int n = mt * 16 + quad * 4 + reg;         // token row 0..63
          cbase[n * 40] = (f16)(acc[mt][nt][reg] + bc);
        }
    }
    __syncthreads();
    // 8 chunks x 32 threads; each thread: 2 rows x 4 x 16B stores (fully coalesced)
    const int ch = tid >> 5, tt = tid & 31;
    const int which = xn / 3;                       // 0..2, constant per block
    const long b = (long)ym * 2 + (ch >> 2);        // window
    const int hh = (xn - which * 3) * 4 + (ch & 3); // head
    f16* dst = (f16*)out + ((long)which * (NWIN * NH) + b * NH + hh) * 2048;
#pragma unroll
    for (int rr = 0; rr < 2; rr++) {
      const int n = tt * 2 + rr;
      const f16* src = smem + (ch * 64 + n) * 40;
      f16* drow = dst + n * 32;
#pragma unroll
      for (int j = 0; j < 4; j++)
        *(f16x8*)(drow + j * 8) = *(const f16x8*)(src + j * 8);
    }
  } else {
#pragma unroll
    for (int mt = 0; mt < 4; mt++) {
#pragma unroll
      for (int nt = 0; nt < 4; nt++) {
        int c = xn * 128 + wn * 64 + nt * 16 + col0;
        float bc = bias[c];
#pragma unroll
        for (int reg = 0; reg < 4; reg++) {
          long m = arow + wm * 64 + mt * 16 + quad * 4 + reg;
          float v = acc[mt][nt][reg] + bc;
          ((float*)out)[m * 384 + c] = v;
        }
      }
    }
  }
}

// ---------------- fused window attention: one block per (b,h) ----------------
__global__ __launch_bounds__(256) void k_attn(const f16* __restrict__ qkv,
                                              const float* __restrict__ mask,
                                              const float* __restrict__ bias,
                                              const float* __restrict__ lsc,
                                              f16* __restrict__ aout) {
  __shared__ f16 qs[64 * 32];
  __shared__ f16 ks[64 * 32];
  __shared__ f16 vt[32 * 72];   // V^T, padded
  __shared__ float sm[64 * 64]; // bias + mask
  __shared__ f16 ps[64 * 72];   // P, padded

  const int bh = blockIdx.x;
  const int b = bh / NH;
  const int h = bh - b * NH;
  const int w = b & 1023;  // b % nW
  const int tid = threadIdx.x;
  const int lane = tid & 63, wid = tid >> 6;

  const long HB = (long)NWIN * NH * 64 * 32;
  const f16* qg = qkv + (long)bh * 2048;

  // cooperative load q,k,v (each 64x32 f16 = 4KB); 8 f16 per thread
  f16x8 qv = ((const f16x8*)qg)[tid];
  f16x8 kv = ((const f16x8*)(qg + HB))[tid];
  f16x8 vv = ((const f16x8*)(qg + 2 * HB))[tid];

  // row norms (4 threads per row of 32)
  float ssq = 0.f, ssk = 0.f;
#pragma unroll
  for (int j = 0; j < 8; j++) {
    float xq = (float)qv[j]; ssq += xq * xq;
    float xk = (float)kv[j]; ssk += xk * xk;
  }
  ssq += __shfl_xor(ssq, 1); ssq += __shfl_xor(ssq, 2);
  ssk += __shfl_xor(ssk, 1); ssk += __shfl_xor(ssk, 2);
  float lscale = __expf(fminf(lsc[h], 4.6051701860f));  // exp(min(ls, log(100)))
  float qsc = lscale / fmaxf(sqrtf(ssq), 1e-12f);
  float ksc = 1.f / fmaxf(sqrtf(ssk), 1e-12f);

  f16x8 qn, kn;
#pragma unroll
  for (int j = 0; j < 8; j++) {
    qn[j] = (f16)((float)qv[j] * qsc);
    kn[j] = (f16)((float)kv[j] * ksc);
  }
  ((f16x8*)qs)[tid] = qn;
  ((f16x8*)ks)[tid] = kn;
  {
    int vrow = tid >> 2, d0 = (tid & 3) * 8;
#pragma unroll
    for (int j = 0; j < 8; j++) vt[(d0 + j) * 72 + vrow] = vv[j];
  }
  // stage bias+mask sum into LDS (fp32)
  {
    const float4* bp = (const float4*)(bias + (long)h * 4096);
    const float4* mp = (const float4*)(mask + (long)w * 4096);
#pragma unroll
    for (int j = 0; j < 4; j++) {
      int i4 = tid + 256 * j;
      float4 bb = bp[i4];
      float4 mm = mp[i4];
      bb.x += mm.x; bb.y += mm.y; bb.z += mm.z; bb.w += mm.w;
      ((float4*)sm)[i4] = bb;
    }
  }
  __syncthreads();

  const int col0 = lane & 15, quad = lane >> 4;
  // S = q_hat * k_hat^T  (wave wid owns query rows [16*wid, 16*wid+16))
  f16x8 aq = *(const f16x8*)&qs[(wid * 16 + col0) * 32 + quad * 8];
  f32x4 s[4];
#pragma unroll
  for (int nt = 0; nt < 4; nt++) {
    f16x8 bk = *(const f16x8*)&ks[(nt * 16 + col0) * 32 + quad * 8];
    f32x4 z = {};
    s[nt] = __builtin_amdgcn_mfma_f32_16x16x32_f16(aq, bk, z, 0, 0, 0);
  }

  float rinv[4];
#pragma unroll
  for (int reg = 0; reg < 4; reg++) {
    int r = wid * 16 + quad * 4 + reg;
    float m_ = -1e30f;
#pragma unroll
    for (int nt = 0; nt < 4; nt++) {
      s[nt][reg] += sm[r * 64 + nt * 16 + col0];
      m_ = fmaxf(m_, s[nt][reg]);
    }
    m_ = fmaxf(m_, __shfl_xor(m_, 1));
    m_ = fmaxf(m_, __shfl_xor(m_, 2));
    m_ = fmaxf(m_, __shfl_xor(m_, 4));
    m_ = fmaxf(m_, __shfl_xor(m_, 8));
    float l_ = 0.f;
#pragma unroll
    for (int nt = 0; nt < 4; nt++) {
      float p = __expf(s[nt][reg] - m_);
      s[nt][reg] = p;
      l_ += p;
    }
    l_ += __shfl_xor(l_, 1);
    l_ += __shfl_xor(l_, 2);
    l_ += __shfl_xor(l_, 4);
    l_ += __shfl_xor(l_, 8);
    rinv[reg] = 1.f / l_;
#pragma unroll
    for (int nt = 0; nt < 4; nt++) ps[r * 72 + nt * 16 + col0] = (f16)s[nt][reg];
  }
  __syncthreads();

  // O = P * V   (K=64 keys in 2 steps; N=32 dims in 2 tiles)
  f32x4 o[2] = {};
#pragma unroll
  for (int kkk = 0; kkk < 2; kkk++) {
    f16x8 ap = *(const f16x8*)&ps[(wid * 16 + col0) * 72 + kkk * 32 + quad * 8];
#pragma unroll
    for (int nt = 0; nt < 2; nt++) {
      f16x8 bv = *(const f16x8*)&vt[(nt * 16 + col0) * 72 + kkk * 32 + quad * 8];
      o[nt] = __builtin_amdgcn_mfma_f32_16x16x32_f16(ap, bv, o[nt], 0, 0, 0);
    }
  }
#pragma unroll
  for (int nt = 0; nt < 2; nt++)
#pragma unroll
    for (int reg = 0; reg < 4; reg++) {
      int r = wid * 16 + quad * 4 + reg;
      int d = nt * 16 + col0;
      float v = o[nt][reg] * rinv[reg];
      aout[((long)b * 64 + r) * 384 + h * 32 + d] = (f16)v;
    }
}

// ---------------- launch ----------------

extern "C" void kernel_launch(void* const* d_in, const int* in_sizes, int n_in,
                              void* d_out, int out_size, void* d_ws, size_t ws_size,
                              hipStream_t stream) {
  const float* x      = (const float*)d_in[0];
  const float* mask   = (const float*)d_in[1];
  const float* qkv_w  = (const float*)d_in[2];
  const float* qkv_b  = (const float*)d_in[3];
  const float* proj_w = (const float*)d_in[4];
  const float* proj_b = (const float*)d_in[5];
  const float* lsc    = (const float*)d_in[6];
  const float* cpb_w1 = (const float*)d_in[7];
  const float* cpb_b1 = (const float*)d_in[8];
  const float* cpb_w2 = (const float*)d_in[9];
  const float* table  = (const float*)d_in[10];
  const int* ridx     = (const int*)d_in[11];
  float* out = (float*)d_out;

  char* ws = (char*)d_ws;
  const long NQKV = (long)3 * NWIN * NH * 64 * 32;  // 301,989,888 f16
  f16* qkvbuf = (f16*)ws;                                            // 603,979,776 B
  f16* xh     = (f16*)(ws + NQKV * 2);                               // 201,326,592 B
  f16* aoutbuf = xh;  // alias: xh is dead once qkv gemm has run
  f16* wtq    = (f16*)(ws + NQKV * 2 + 201326592L);                  // 884,736 B
  f16* wtp    = (f16*)(ws + NQKV * 2 + 201326592L + 884736L);        // 294,912 B
  float* biasbuf = (float*)(ws + NQKV * 2 + 201326592L + 884736L + 294912L);  // 196,608 B

  // prep
  k_cvt_x<<<4096, 256, 0, stream>>>(x, xh, 100663296L / 4);
  k_transpose<<<(1152 * 384) / 256, 256, 0, stream>>>(qkv_w, wtq, 384, 1152);
  k_transpose<<<(384 * 384) / 256, 256, 0, stream>>>(proj_w, wtp, 384, 384);
  k_cpb<<<64, 64, 0, stream>>>(table, ridx, cpb_w1, cpb_b1, cpb_w2, biasbuf);

  // qkv gemm: M=262144, K=384, N=1152
  k_gemm<0, 9><<<2048 * 9, 256, 0, stream>>>(xh, wtq, qkv_b, qkvbuf, 384);

  // fused attention per (b,h)
  k_attn<<<NWIN * NH, 256, 0, stream>>>(qkvbuf, mask, biasbuf, lsc, aoutbuf);

  // proj gemm: M=262144, K=384, N=384
  k_gemm<1, 3><<<2048 * 3, 256, 0, stream>>>(aoutbuf, wtp, proj_b, out, 384);
}

// Round 2
// 1505.616 us; speedup vs baseline: 1.0429x; 1.0429x over previous
//
#include <hip/hip_runtime.h>
#include <hip/hip_fp16.h>

typedef _Float16 f16;
typedef _Float16 f16x8 __attribute__((ext_vector_type(8)));
typedef _Float16 f16x4 __attribute__((ext_vector_type(4)));
typedef float f32x4 __attribute__((ext_vector_type(4)));

#define NH 12
#define NWIN 4096
// tokens per window = 64, head dim = 32, DIM = 384, qkv N = 1152

__device__ __forceinline__ void gload16(const void* g, void* l) {
  __builtin_amdgcn_global_load_lds(
      (const __attribute__((address_space(1))) void*)g,
      (__attribute__((address_space(3))) void*)l, 16, 0, 0);
}

// ---------------- prep kernels ----------------

__global__ __launch_bounds__(256) void k_cvt_x(const float* __restrict__ in,
                                               f16* __restrict__ out, long n4) {
  long i = (long)blockIdx.x * 256 + threadIdx.x;
  long stride = (long)gridDim.x * 256;
  for (; i < n4; i += stride) {
    float4 v = ((const float4*)in)[i];
    f16x4 o = {(f16)v.x, (f16)v.y, (f16)v.z, (f16)v.w};
    ((f16x4*)out)[i] = o;
  }
}

// out[n*K + k] = in[k*N + n]  (cast to f16)
__global__ __launch_bounds__(256) void k_transpose(const float* __restrict__ in,
                                                   f16* __restrict__ out, int K, int N) {
  long i = (long)blockIdx.x * 256 + threadIdx.x;
  if (i >= (long)K * N) return;
  int n = (int)(i / K);
  int k = (int)(i - (long)n * K);
  out[i] = (f16)in[(long)k * N + n];
}

// continuous position bias: bias[h][p] = 16*sigmoid( MLP(table[rel_pos_index[p]]) . w2[:,h] )
__global__ __launch_bounds__(64) void k_cpb(const float* __restrict__ table,
                                            const int* __restrict__ ridx,
                                            const float* __restrict__ w1,
                                            const float* __restrict__ b1,
                                            const float* __restrict__ w2,
                                            float* __restrict__ biasout) {
  int p = blockIdx.x * 64 + threadIdx.x;  // 0..4095
  int idx = ridx[p];
  float t0 = table[idx * 2], t1 = table[idx * 2 + 1];
  float acc[NH] = {};
  for (int u = 0; u < 512; u++) {
    float hv = fmaxf(t0 * w1[u] + t1 * w1[512 + u] + b1[u], 0.f);
#pragma unroll
    for (int h = 0; h < NH; h++) acc[h] += hv * w2[u * NH + h];
  }
  for (int h = 0; h < NH; h++) biasout[h * 4096 + p] = 16.f / (1.f + __expf(-acc[h]));
}

// ---------------- GEMM: C[M x N] = A[M x K] * Bt[N x K]^T + bias ----------------
// 2-phase double-buffered K-loop (T3-minimum): STAGE(next) -> compute(cur) ->
// one barrier per k-step whose forced vmcnt(0) drains loads that had the whole
// compute phase to land. LDS = 2 x (As 8KB + Bs 8KB) = 32 KB -> 5 blocks/CU.
// MODE 0: qkv gemm (N=1152), f16 scatter out to [3][b*12+h][64][32]
// MODE 1: proj gemm (N=384), fp32 out row-major [M][384]
template <int MODE, int NXB>
__global__ __launch_bounds__(256) void k_gemm(const f16* __restrict__ A,
                                              const f16* __restrict__ Bt,
                                              const float* __restrict__ bias,
                                              void* __restrict__ out, int K) {
  __shared__ f16 smem[2 * 8192];  // [buf][As 4096 f16 | Bs 4096 f16]
  const int lin = blockIdx.x;
  // XCD swizzle: all NXB column-blocks of one row-block share lin%8 -> same XCD L2
  const int idx = lin % (NXB * 8);
  const int xn = idx >> 3;
  const int ym = (lin / (NXB * 8)) * 8 + (idx & 7);
  const int tid = threadIdx.x;
  const int lane = tid & 63, wid = tid >> 6;
  const int wm = wid & 1, wn = wid >> 1;

  f32x4 acc[4][4] = {};
  const long arow = (long)ym * 128;
  const long brow = (long)xn * 128;

  // per-thread global source addressing (j=0 row; j=1 adds 16 rows)
  const int r0 = wid * 32 + (lane >> 2);
  const int co0 = (lane & 3) * 8;
  const f16* aptr = A + (arow + r0) * K + co0;
  const f16* bptr = Bt + (brow + r0) * K + co0;

#define STAGE(buf, kk)                                                              \
  {                                                                                 \
    _Pragma("unroll") for (int j = 0; j < 2; j++) {                                 \
      gload16(aptr + (long)(j * 16) * K + (kk),                                     \
              smem + (buf) * 8192 + (wid * 32 + j * 16) * 32);                      \
      gload16(bptr + (long)(j * 16) * K + (kk),                                     \
              smem + (buf) * 8192 + 4096 + (wid * 32 + j * 16) * 32);               \
    }                                                                               \
  }

  STAGE(0, 0);
  __syncthreads();  // prologue drain (full latency, paid once)
  int cur = 0;
#pragma unroll 1
  for (int kk = 0; kk < K; kk += 32) {
    if (kk + 32 < K) STAGE(cur ^ 1, kk + 32);  // async issue next tile
    const f16* As = smem + cur * 8192;
    const f16* Bs = As + 4096;
    f16x8 am[4], bn[4];
#pragma unroll
    for (int t = 0; t < 4; t++) {
      am[t] = *(const f16x8*)&As[(wm * 64 + t * 16 + (lane & 15)) * 32 + (lane >> 4) * 8];
      bn[t] = *(const f16x8*)&Bs[(wn * 64 + t * 16 + (lane & 15)) * 32 + (lane >> 4) * 8];
    }
#pragma unroll
    for (int mt = 0; mt < 4; mt++)
#pragma unroll
      for (int nt = 0; nt < 4; nt++)
        acc[mt][nt] = __builtin_amdgcn_mfma_f32_16x16x32_f16(am[mt], bn[nt], acc[mt][nt], 0, 0, 0);
    __syncthreads();  // drains this iter's stage loads (overlapped with compute)
    cur ^= 1;
  }
#undef STAGE

  const int quad = lane >> 4, col0 = lane & 15;
#pragma unroll
  for (int mt = 0; mt < 4; mt++) {
#pragma unroll
    for (int nt = 0; nt < 4; nt++) {
      int c = xn * 128 + wn * 64 + nt * 16 + col0;
      float bc = bias[c];
#pragma unroll
      for (int reg = 0; reg < 4; reg++) {
        long m = arow + wm * 64 + mt * 16 + quad * 4 + reg;
        float v = acc[mt][nt][reg] + bc;
        if (MODE == 0) {
          int which = c / 384;
          int rem = c - which * 384;
          int hh = rem >> 5, d = rem & 31;
          long b = m >> 6;
          long n = m & 63;
          ((f16*)out)[(((long)which * (NWIN * NH) + b * NH + hh) * 64 + n) * 32 + d] = (f16)v;
        } else {
          ((float*)out)[m * 384 + c] = v;
        }
      }
    }
  }
}

// ---------------- fused window attention: one block per (b,h) ----------------
__global__ __launch_bounds__(256) void k_attn(const f16* __restrict__ qkv,
                                              const float* __restrict__ mask,
                                              const float* __restrict__ bias,
                                              const float* __restrict__ lsc,
                                              f16* __restrict__ aout) {
  __shared__ f16 qs[64 * 32];
  __shared__ f16 ks[64 * 32];
  __shared__ f16 vt[32 * 72];   // V^T, padded
  __shared__ float sm[64 * 64]; // bias + mask
  __shared__ f16 ps[64 * 72];   // P, padded

  const int bh = blockIdx.x;
  const int b = bh / NH;
  const int h = bh - b * NH;
  const int w = b & 1023;  // b % nW
  const int tid = threadIdx.x;
  const int lane = tid & 63, wid = tid >> 6;

  const long HB = (long)NWIN * NH * 64 * 32;
  const f16* qg = qkv + (long)bh * 2048;

  // cooperative load q,k,v (each 64x32 f16 = 4KB); 8 f16 per thread
  f16x8 qv = ((const f16x8*)qg)[tid];
  f16x8 kv = ((const f16x8*)(qg + HB))[tid];
  f16x8 vv = ((const f16x8*)(qg + 2 * HB))[tid];

  // row norms (4 threads per row of 32)
  float ssq = 0.f, ssk = 0.f;
#pragma unroll
  for (int j = 0; j < 8; j++) {
    float xq = (float)qv[j]; ssq += xq * xq;
    float xk = (float)kv[j]; ssk += xk * xk;
  }
  ssq += __shfl_xor(ssq, 1); ssq += __shfl_xor(ssq, 2);
  ssk += __shfl_xor(ssk, 1); ssk += __shfl_xor(ssk, 2);
  float lscale = __expf(fminf(lsc[h], 4.6051701860f));  // exp(min(ls, log(100)))
  float qsc = lscale / fmaxf(sqrtf(ssq), 1e-12f);
  float ksc = 1.f / fmaxf(sqrtf(ssk), 1e-12f);

  f16x8 qn, kn;
#pragma unroll
  for (int j = 0; j < 8; j++) {
    qn[j] = (f16)((float)qv[j] * qsc);
    kn[j] = (f16)((float)kv[j] * ksc);
  }
  ((f16x8*)qs)[tid] = qn;
  ((f16x8*)ks)[tid] = kn;
  {
    int vrow = tid >> 2, d0 = (tid & 3) * 8;
#pragma unroll
    for (int j = 0; j < 8; j++) vt[(d0 + j) * 72 + vrow] = vv[j];
  }
  // stage bias+mask sum into LDS (fp32)
  {
    const float4* bp = (const float4*)(bias + (long)h * 4096);
    const float4* mp = (const float4*)(mask + (long)w * 4096);
#pragma unroll
    for (int j = 0; j < 4; j++) {
      int i4 = tid + 256 * j;
      float4 bb = bp[i4];
      float4 mm = mp[i4];
      bb.x += mm.x; bb.y += mm.y; bb.z += mm.z; bb.w += mm.w;
      ((float4*)sm)[i4] = bb;
    }
  }
  __syncthreads();

  const int col0 = lane & 15, quad = lane >> 4;
  // S = q_hat * k_hat^T  (wave wid owns query rows [16*wid, 16*wid+16))
  f16x8 aq = *(const f16x8*)&qs[(wid * 16 + col0) * 32 + quad * 8];
  f32x4 s[4];
#pragma unroll
  for (int nt = 0; nt < 4; nt++) {
    f16x8 bk = *(const f16x8*)&ks[(nt * 16 + col0) * 32 + quad * 8];
    f32x4 z = {};
    s[nt] = __builtin_amdgcn_mfma_f32_16x16x32_f16(aq, bk, z, 0, 0, 0);
  }

  float rinv[4];
#pragma unroll
  for (int reg = 0; reg < 4; reg++) {
    int r = wid * 16 + quad * 4 + reg;
    float m_ = -1e30f;
#pragma unroll
    for (int nt = 0; nt < 4; nt++) {
      s[nt][reg] += sm[r * 64 + nt * 16 + col0];
      m_ = fmaxf(m_, s[nt][reg]);
    }
    m_ = fmaxf(m_, __shfl_xor(m_, 1));
    m_ = fmaxf(m_, __shfl_xor(m_, 2));
    m_ = fmaxf(m_, __shfl_xor(m_, 4));
    m_ = fmaxf(m_, __shfl_xor(m_, 8));
    float l_ = 0.f;
#pragma unroll
    for (int nt = 0; nt < 4; nt++) {
      float p = __expf(s[nt][reg] - m_);
      s[nt][reg] = p;
      l_ += p;
    }
    l_ += __shfl_xor(l_, 1);
    l_ += __shfl_xor(l_, 2);
    l_ += __shfl_xor(l_, 4);
    l_ += __shfl_xor(l_, 8);
    rinv[reg] = 1.f / l_;
#pragma unroll
    for (int nt = 0; nt < 4; nt++) ps[r * 72 + nt * 16 + col0] = (f16)s[nt][reg];
  }
  __syncthreads();

  // O = P * V   (K=64 keys in 2 steps; N=32 dims in 2 tiles)
  f32x4 o[2] = {};
#pragma unroll
  for (int kkk = 0; kkk < 2; kkk++) {
    f16x8 ap = *(const f16x8*)&ps[(wid * 16 + col0) * 72 + kkk * 32 + quad * 8];
#pragma unroll
    for (int nt = 0; nt < 2; nt++) {
      f16x8 bv = *(const f16x8*)&vt[(nt * 16 + col0) * 72 + kkk * 32 + quad * 8];
      o[nt] = __builtin_amdgcn_mfma_f32_16x16x32_f16(ap, bv, o[nt], 0, 0, 0);
    }
  }
#pragma unroll
  for (int nt = 0; nt < 2; nt++)
#pragma unroll
    for (int reg = 0; reg < 4; reg++) {
      int r = wid * 16 + quad * 4 + reg;
      int d = nt * 16 + col0;
      float v = o[nt][reg] * rinv[reg];
      aout[((long)b * 64 + r) * 384 + h * 32 + d] = (f16)v;
    }
}

// ---------------- launch ----------------

extern "C" void kernel_launch(void* const* d_in, const int* in_sizes, int n_in,
                              void* d_out, int out_size, void* d_ws, size_t ws_size,
                              hipStream_t stream) {
  const float* x      = (const float*)d_in[0];
  const float* mask   = (const float*)d_in[1];
  const float* qkv_w  = (const float*)d_in[2];
  const float* qkv_b  = (const float*)d_in[3];
  const float* proj_w = (const float*)d_in[4];
  const float* proj_b = (const float*)d_in[5];
  const float* lsc    = (const float*)d_in[6];
  const float* cpb_w1 = (const float*)d_in[7];
  const float* cpb_b1 = (const float*)d_in[8];
  const float* cpb_w2 = (const float*)d_in[9];
  const float* table  = (const float*)d_in[10];
  const int* ridx     = (const int*)d_in[11];
  float* out = (float*)d_out;

  char* ws = (char*)d_ws;
  const long NQKV = (long)3 * NWIN * NH * 64 * 32;  // 301,989,888 f16
  f16* qkvbuf = (f16*)ws;                                            // 603,979,776 B
  f16* xh     = (f16*)(ws + NQKV * 2);                               // 201,326,592 B
  f16* aoutbuf = xh;  // alias: xh is dead once qkv gemm has run
  f16* wtq    = (f16*)(ws + NQKV * 2 + 201326592L);                  // 884,736 B
  f16* wtp    = (f16*)(ws + NQKV * 2 + 201326592L + 884736L);        // 294,912 B
  float* biasbuf = (float*)(ws + NQKV * 2 + 201326592L + 884736L + 294912L);  // 196,608 B

  // prep
  k_cvt_x<<<4096, 256, 0, stream>>>(x, xh, 100663296L / 4);
  k_transpose<<<(1152 * 384) / 256, 256, 0, stream>>>(qkv_w, wtq, 384, 1152);
  k_transpose<<<(384 * 384) / 256, 256, 0, stream>>>(proj_w, wtp, 384, 384);
  k_cpb<<<64, 64, 0, stream>>>(table, ridx, cpb_w1, cpb_b1, cpb_w2, biasbuf);

  // qkv gemm: M=262144, K=384, N=1152
  k_gemm<0, 9><<<2048 * 9, 256, 0, stream>>>(xh, wtq, qkv_b, qkvbuf, 384);

  // fused attention per (b,h)
  k_attn<<<NWIN * NH, 256, 0, stream>>>(qkvbuf, mask, biasbuf, lsc, aoutbuf);

  // proj gemm: M=262144, K=384, N=384
  k_gemm<1, 3><<<2048 * 3, 256, 0, stream>>>(aoutbuf, wtp, proj_b, out, 384);
}